// Round 3
// baseline (604.249 us; speedup 1.0000x reference)
//
#include <hip/hip_runtime.h>

// LSTM B=256,T=512,I=64,H=128 fp32 — R3 "gate-split".
// 256 blocks (1/CU, persistent per batch row) x 1024 threads.
// thread = (j, r, kh): h-col j in [0,128), gate r in {i,f,g,o}, k-half kh in {0,1}.
// Owns ONE gate row (r*128+j), 96 of 192 unified k -> 96 weight floats.
// amdgpu_waves_per_eu(4,4) pins occupancy so the compiler allocates ~128 ARCH
// VGPRs instead of R2's 64+AGPR-spill (which cost ~96 v_accvgpr_read/step).
// Reduction: ONE dpp xor1 (kh). Activation: unified tanh(x)=2*sig(2x)-1 form,
// one exp + one rcp per gate. c/h update in-register via xor2/xor4 swizzles.
// One barrier per step.

#define BB 256
#define TT 512
#define II 64
#define HH 128
#define KK 192          // unified K = II + HH
#define KPT 96          // K per thread (2-way split)
#define NTH 1024

__device__ __forceinline__ float dpp_xor1(float v) {
    return __int_as_float(__builtin_amdgcn_mov_dpp(__float_as_int(v), 0xB1, 0xF, 0xF, true)); // quad_perm {1,0,3,2}
}
__device__ __forceinline__ float dpp_xor2(float v) {
    return __int_as_float(__builtin_amdgcn_mov_dpp(__float_as_int(v), 0x4E, 0xF, 0xF, true)); // quad_perm {2,3,0,1}
}
__device__ __forceinline__ float swz_xor4(float v) {
    return __int_as_float(__builtin_amdgcn_ds_swizzle(__float_as_int(v), 0x101F)); // xor_mask=4
}
__device__ __forceinline__ float fast_rcp(float x) { return __builtin_amdgcn_rcpf(x); }

__global__ __launch_bounds__(NTH)
__attribute__((amdgpu_waves_per_eu(4, 4)))
void lstm_gatesplit(const float* __restrict__ inputs,   // [B,T,I]
                    const float* __restrict__ h_prev,   // [B,H]
                    const float* __restrict__ c_prev,   // [B,H]
                    const float* __restrict__ W_ih,     // [4H,I]
                    const float* __restrict__ W_hh,     // [4H,H]
                    const float* __restrict__ b_ih,     // [4H]
                    const float* __restrict__ b_hh,     // [4H]
                    float* __restrict__ out)            // outputs|h_last|c_last
{
    const int b   = blockIdx.x;
    const int tid = threadIdx.x;
    const int kh  = tid & 1;          // k half
    const int r   = (tid >> 1) & 3;   // gate: 0=i 1=f 2=g 3=o
    const int j   = tid >> 3;         // h column
    const int row = r * HH + j;       // gate row in [0,512)
    const int k0  = kh * KPT;

    // ---- one gate row's weights, register-resident: unified k {W_ih | W_hh}
    float w[KPT];
    #pragma unroll
    for (int q = 0; q < KPT / 4; ++q) {
        const int k = k0 + 4 * q;
        float4 v = (k < II) ? *(const float4*)(W_ih + (size_t)row * II + k)
                            : *(const float4*)(W_hh + (size_t)row * HH + (k - II));
        w[4*q+0] = v.x; w[4*q+1] = v.y; w[4*q+2] = v.z; w[4*q+3] = v.w;
    }
    const float bias = (kh == 0) ? (b_ih[row] + b_hh[row]) : 0.0f;
    // unified activation: a = am * sigmoid(am * x) + ab  (r==2 -> tanh(x))
    const float am = (r == 2) ? 2.0f : 1.0f;
    const float ab = (r == 2) ? -1.0f : 0.0f;

    __shared__ __align__(16) float xh[2][KK];   // [x(64) | h(128)], double-buffered

    float c = c_prev[(size_t)b * HH + j];       // valid on r==0 lanes (both kh)
    float h = 0.0f;

    const float* xin = inputs + (size_t)b * TT * II;
    if (tid < II) xh[0][tid] = xin[tid];
    if ((tid & 7) == 0) xh[0][II + j] = h_prev[(size_t)b * HH + j];
    __syncthreads();

    float* outp = out + (size_t)b * TT * HH;
    float* cur = xh[0];
    float* nxt = xh[1];

    for (int t = 0; t < TT; ++t) {
        // prefetch next x (latency hidden under the 96-FMA GEMV)
        float xpre = 0.0f;
        if (tid < II) {
            const int tn = (t + 1 < TT) ? (t + 1) : (TT - 1);
            xpre = xin[(size_t)tn * II + tid];
        }

        // ---- 96 FMAs, one gate row x 96 k (LDS reads: 2 distinct addrs/wave = broadcast)
        float acc = bias;
        const float4* xc = (const float4*)(cur + k0);
        #pragma unroll
        for (int q = 0; q < KPT / 4; ++q) {
            const float4 v = xc[q];
            acc = fmaf(w[4*q+0], v.x, acc);
            acc = fmaf(w[4*q+1], v.y, acc);
            acc = fmaf(w[4*q+2], v.z, acc);
            acc = fmaf(w[4*q+3], v.w, acc);
        }

        // ---- single reduction stage: sum the two k-halves (lane bit 0)
        acc += dpp_xor1(acc);

        // ---- unified activation: one exp + one rcp for all four gate types
        const float e = __expf(-(am * acc));
        const float s = fast_rcp(1.0f + e);
        const float a = fmaf(am, s, ab);        // i,f,o: sigmoid; g: tanh

        // ---- gather i,f,g,o across lanes (r = lane bits 1-2) and update state.
        // Values are correct on r==0 lanes; others compute harmless garbage.
        const float ig = a * swz_xor4(a);       // r=0: a(i) * a(g~)  [xor4 flips r bit1]
        const float f  = dpp_xor2(a);           // r=0: a(f)          [xor2 flips r bit0]
        const float o  = swz_xor4(f);           // r=0: a(o)
        c = fmaf(f, c, ig);
        const float e2 = __expf(-2.0f * c);
        const float th = fmaf(2.0f, fast_rcp(1.0f + e2), -1.0f);  // tanh(c)
        h = o * th;

        if ((tid & 7) == 0) {                   // (r==0, kh==0) owns column j
            nxt[II + j] = h;
            outp[(size_t)t * HH + j] = h;
        }
        if (tid < II) nxt[tid] = xpre;
        __syncthreads();                        // single barrier per step
        float* tmp = cur; cur = nxt; nxt = tmp;
    }

    if ((tid & 7) == 0) {
        out[(size_t)BB * TT * HH + (size_t)b * HH + j] = h;
        out[(size_t)BB * TT * HH + (size_t)BB * HH + (size_t)b * HH + j] = c;
    }
}

extern "C" void kernel_launch(void* const* d_in, const int* in_sizes, int n_in,
                              void* d_out, int out_size, void* d_ws, size_t ws_size,
                              hipStream_t stream) {
    const float* inputs = (const float*)d_in[0];
    const float* h_prev = (const float*)d_in[1];
    const float* c_prev = (const float*)d_in[2];
    const float* W_ih   = (const float*)d_in[3];
    const float* W_hh   = (const float*)d_in[4];
    const float* b_ih   = (const float*)d_in[5];
    const float* b_hh   = (const float*)d_in[6];
    float* outp = (float*)d_out;

    lstm_gatesplit<<<dim3(BB), dim3(NTH), 0, stream>>>(
        inputs, h_prev, c_prev, W_ih, W_hh, b_ih, b_hh, outp);
}

// Round 4
// 561.310 us; speedup vs baseline: 1.0765x; 1.0765x over previous
//
#include <hip/hip_runtime.h>

// LSTM B=256,T=512,I=64,H=128 fp32 — R4 = R2 structure + forced VGPR budget.
//
// R2/R3 post-mortem: VGPR_Count=64 both rounds -> the 96 weight floats/thread
// were AGPR-spilled (gfx950 unified file), costing ~1 extra issue op per weight
// per step (~2.5x VALU bloat). Cause: tiny LDS (1.5KB) let the compiler target
// 2 blocks/CU (32 waves) -> 64-VGPR cap. Fix: carve the real buffers out of a
// 100KB LDS arena -> only 1 block/CU fits -> 16 waves = 4/EU -> allocator
// budget rises to 128 VGPRs, enough for 96 weights + ~30 working set.
//
// Layout (R2, best measured): 256 blocks (1/CU, persistent per batch row) x
// 1024 threads. thread = (j, ks): h-col j in [0,128), k-slice ks in [0,8).
// Owns 4 gate rows {j, j+128, j+256, j+384} x 24 unified-k -> 96 weights.
// Per step: 96 FMAs in 4 independent 24-chains; butterfly reduce over 8
// ks-lanes (dpp xor1/xor2 + ds_swizzle xor4); c,h update in registers;
// ONE barrier per step.

#define BB 256
#define TT 512
#define II 64
#define HH 128
#define KK 192          // II + HH unified K
#define KS 8            // k-split factor
#define KPT (KK / KS)   // 24 k per thread
#define NTH (HH * KS)   // 1024 threads

// 100 KB LDS arena: forces 1 block/CU (occupancy-derived 128-VGPR budget).
#define LDS_FLOATS 25088

__device__ __forceinline__ float dpp_xor1(float v) {
    return __int_as_float(__builtin_amdgcn_mov_dpp(__float_as_int(v), 0xB1, 0xF, 0xF, true)); // quad_perm {1,0,3,2}
}
__device__ __forceinline__ float dpp_xor2(float v) {
    return __int_as_float(__builtin_amdgcn_mov_dpp(__float_as_int(v), 0x4E, 0xF, 0xF, true)); // quad_perm {2,3,0,1}
}
__device__ __forceinline__ float swz_xor4(float v) {
    return __int_as_float(__builtin_amdgcn_ds_swizzle(__float_as_int(v), 0x101F)); // xor_mask=4
}
__device__ __forceinline__ float fast_sigmoid(float x) {
    float e = __expf(-x);
    return __builtin_amdgcn_rcpf(1.0f + e);
}
__device__ __forceinline__ float fast_tanh(float x) {
    float e = __expf(2.0f * x);                       // +inf ok -> rcp -> 0 -> 1
    return 1.0f - 2.0f * __builtin_amdgcn_rcpf(e + 1.0f);
}

__global__ __launch_bounds__(NTH, 4)
void lstm_split(const float* __restrict__ inputs,   // [B,T,I]
                const float* __restrict__ h_prev,   // [B,H]
                const float* __restrict__ c_prev,   // [B,H]
                const float* __restrict__ W_ih,     // [4H,I]
                const float* __restrict__ W_hh,     // [4H,H]
                const float* __restrict__ b_ih,     // [4H]
                const float* __restrict__ b_hh,     // [4H]
                float* __restrict__ out)            // outputs|h_last|c_last
{
    const int b   = blockIdx.x;
    const int tid = threadIdx.x;
    const int j   = tid >> 3;     // h column
    const int ks  = tid & 7;      // k slice
    const int k0  = ks * KPT;

    __shared__ __align__(16) float lds_all[LDS_FLOATS];
    float* xh0 = lds_all;          // [x(64) | h(128)] buffer 0
    float* xh1 = lds_all + 256;    // buffer 1 (1 KB offset, 16B aligned)

    // ---- register-resident weights: unified k axis {W_ih row | W_hh row}
    float w[4][KPT];
    #pragma unroll
    for (int r = 0; r < 4; ++r) {
        const int row = j + r * HH;
        #pragma unroll
        for (int g = 0; g < KPT / 4; ++g) {
            const int k = k0 + 4 * g;
            float4 v = (k < II) ? *(const float4*)(W_ih + (size_t)row * II + k)
                                : *(const float4*)(W_hh + (size_t)row * HH + (k - II));
            w[r][4*g+0] = v.x; w[r][4*g+1] = v.y; w[r][4*g+2] = v.z; w[r][4*g+3] = v.w;
        }
    }
    // bias contributed by the ks==0 lane only (post-reduction sum gets it once)
    float bias[4];
    #pragma unroll
    for (int r = 0; r < 4; ++r) {
        const int row = j + r * HH;
        bias[r] = (ks == 0) ? (b_ih[row] + b_hh[row]) : 0.0f;
    }

    float c = c_prev[(size_t)b * HH + j];       // replicated across 8 ks-lanes
    float h = 0.0f;

    const float* xin = inputs + (size_t)b * TT * II;
    if (ks == 0) xh0[II + j] = h_prev[(size_t)b * HH + j];
    if (tid < II) xh0[tid] = xin[tid];
    __syncthreads();

    float* outp = out + (size_t)b * TT * HH;
    float* cur = xh0;
    float* nxt = xh1;

    for (int t = 0; t < TT; ++t) {
        // prefetch next x into regs (latency hidden under GEMV)
        float xpre = 0.0f;
        if (tid < II) {
            const int tn = (t + 1 < TT) ? (t + 1) : (TT - 1);
            xpre = xin[(size_t)tn * II + tid];
        }

        // ---- 96 FMAs: 4 gate rows x 24 k, 4 independent chains (len 24)
        float a0 = bias[0], a1 = bias[1], a2 = bias[2], a3 = bias[3];
        const float4* xc = (const float4*)(cur + k0);
        #pragma unroll
        for (int g = 0; g < KPT / 4; ++g) {
            const float4 v = xc[g];   // 8 distinct addrs/wave, broadcast-friendly
            a0 = fmaf(w[0][4*g+0], v.x, a0); a1 = fmaf(w[1][4*g+0], v.x, a1);
            a2 = fmaf(w[2][4*g+0], v.x, a2); a3 = fmaf(w[3][4*g+0], v.x, a3);
            a0 = fmaf(w[0][4*g+1], v.y, a0); a1 = fmaf(w[1][4*g+1], v.y, a1);
            a2 = fmaf(w[2][4*g+1], v.y, a2); a3 = fmaf(w[3][4*g+1], v.y, a3);
            a0 = fmaf(w[0][4*g+2], v.z, a0); a1 = fmaf(w[1][4*g+2], v.z, a1);
            a2 = fmaf(w[2][4*g+2], v.z, a2); a3 = fmaf(w[3][4*g+2], v.z, a3);
            a0 = fmaf(w[0][4*g+3], v.w, a0); a1 = fmaf(w[1][4*g+3], v.w, a1);
            a2 = fmaf(w[2][4*g+3], v.w, a2); a3 = fmaf(w[3][4*g+3], v.w, a3);
        }

        // ---- butterfly over the 8 ks-lanes (lanes j*8+ks, xor {1,2,4})
        a0 += dpp_xor1(a0); a0 += dpp_xor2(a0); a0 += swz_xor4(a0);
        a1 += dpp_xor1(a1); a1 += dpp_xor2(a1); a1 += swz_xor4(a1);
        a2 += dpp_xor1(a2); a2 += dpp_xor2(a2); a2 += swz_xor4(a2);
        a3 += dpp_xor1(a3); a3 += dpp_xor2(a3); a3 += swz_xor4(a3);

        // ---- gates + state update, all lanes redundantly (no divergence)
        const float ig = fast_sigmoid(a0);
        const float fg = fast_sigmoid(a1);
        const float gg = fast_tanh(a2);
        const float og = fast_sigmoid(a3);
        c = fmaf(fg, c, ig * gg);
        h = og * fast_tanh(c);

        if (ks == 0) {
            nxt[II + j] = h;
            outp[(size_t)t * HH + j] = h;
        }
        if (tid < II) nxt[tid] = xpre;
        __syncthreads();                 // single barrier per step
        float* tmp = cur; cur = nxt; nxt = tmp;
    }

    if (ks == 0) {
        out[(size_t)BB * TT * HH + (size_t)b * HH + j] = h;
        out[(size_t)BB * TT * HH + (size_t)BB * HH + (size_t)b * HH + j] = c;
    }
}

extern "C" void kernel_launch(void* const* d_in, const int* in_sizes, int n_in,
                              void* d_out, int out_size, void* d_ws, size_t ws_size,
                              hipStream_t stream) {
    const float* inputs = (const float*)d_in[0];
    const float* h_prev = (const float*)d_in[1];
    const float* c_prev = (const float*)d_in[2];
    const float* W_ih   = (const float*)d_in[3];
    const float* W_hh   = (const float*)d_in[4];
    const float* b_ih   = (const float*)d_in[5];
    const float* b_hh   = (const float*)d_in[6];
    float* outp = (float*)d_out;

    lstm_split<<<dim3(BB), dim3(NTH), 0, stream>>>(
        inputs, h_prev, c_prev, W_ih, W_hh, b_ih, b_hh, outp);
}

// Round 7
// 473.041 us; speedup vs baseline: 1.2774x; 1.1866x over previous
//
#include <hip/hip_runtime.h>

// LSTM B=256,T=512,I=64,H=128 fp32 — R6 resubmit (R7): R2 math, 512-thread
// blocks, full register residency. (R6 bench never ran: GPU acquisition
// timeout. No counter data; kernel unchanged.)
//
// Key fix vs R2-R4: per-SIMD unified VGPR pool is 512 regs (occupancy steps at
// 64/128/256, m69). A 1024-thr block forces >=4 waves/SIMD -> 128 regs/wave ->
// 96-float weight arrays can never be arch-resident (R2-R4 all showed VGPR=64
// + AGPR-tax). 512-thr block + amdgpu_waves_per_eu(2,2) -> budget 256/wave;
// 192 weights + ~35 working set fits in ARCH VGPRs.
//
// 256 blocks (1/CU, persistent per batch row) x 512 threads.
// thread = (j, ks): h-col j in [0,128), k-slice ks in [0,4).
// Owns 4 gate rows {j, j+128, j+256, j+384} x 48 unified-k -> 192 weights.
// Per step: 192 FMAs in 4 independent chains; 2-stage quad butterfly (pure
// VALU DPP quad_perm, no LDS); c,h update in registers; ONE barrier per step.

#define BB 256
#define TT 512
#define II 64
#define HH 128
#define KK 192          // II + HH unified K
#define KS 4            // k-split factor
#define KPT (KK / KS)   // 48 k per thread
#define NTH (HH * KS)   // 512 threads

__device__ __forceinline__ float dpp_xor1(float v) {
    return __int_as_float(__builtin_amdgcn_mov_dpp(__float_as_int(v), 0xB1, 0xF, 0xF, true)); // quad_perm {1,0,3,2}
}
__device__ __forceinline__ float dpp_xor2(float v) {
    return __int_as_float(__builtin_amdgcn_mov_dpp(__float_as_int(v), 0x4E, 0xF, 0xF, true)); // quad_perm {2,3,0,1}
}
__device__ __forceinline__ float fast_sigmoid(float x) {
    float e = __expf(-x);
    return __builtin_amdgcn_rcpf(1.0f + e);
}
__device__ __forceinline__ float fast_tanh(float x) {
    float e = __expf(2.0f * x);                       // +inf ok -> rcp -> 0 -> 1
    return 1.0f - 2.0f * __builtin_amdgcn_rcpf(e + 1.0f);
}

__global__ __launch_bounds__(NTH)
__attribute__((amdgpu_waves_per_eu(2, 2)))
void lstm_r6(const float* __restrict__ inputs,   // [B,T,I]
             const float* __restrict__ h_prev,   // [B,H]
             const float* __restrict__ c_prev,   // [B,H]
             const float* __restrict__ W_ih,     // [4H,I]
             const float* __restrict__ W_hh,     // [4H,H]
             const float* __restrict__ b_ih,     // [4H]
             const float* __restrict__ b_hh,     // [4H]
             float* __restrict__ out)            // outputs|h_last|c_last
{
    const int b   = blockIdx.x;
    const int tid = threadIdx.x;
    const int j   = tid >> 2;     // h column
    const int ks  = tid & 3;      // k slice (= DPP quad lane)
    const int k0  = ks * KPT;

    __shared__ __align__(16) float xh[2][KK];   // [x(64) | h(128)], double-buffered

    // ---- register-resident weights: unified k axis {W_ih row | W_hh row}
    // (II=64 is float4-aligned, so every float4 chunk lies wholly in x or h.)
    float w[4][KPT];
    #pragma unroll
    for (int r = 0; r < 4; ++r) {
        const int row = j + r * HH;
        #pragma unroll
        for (int g = 0; g < KPT / 4; ++g) {
            const int k = k0 + 4 * g;
            float4 v = (k < II) ? *(const float4*)(W_ih + (size_t)row * II + k)
                                : *(const float4*)(W_hh + (size_t)row * HH + (k - II));
            w[r][4*g+0] = v.x; w[r][4*g+1] = v.y; w[r][4*g+2] = v.z; w[r][4*g+3] = v.w;
        }
    }
    // bias contributed once per quad (ks==0 lane) so the reduced sum has it once
    float bias[4];
    #pragma unroll
    for (int r = 0; r < 4; ++r)
        bias[r] = (ks == 0) ? (b_ih[j + r * HH] + b_hh[j + r * HH]) : 0.0f;

    float c = c_prev[(size_t)b * HH + j];       // replicated across the quad
    float h = 0.0f;

    const float* xin = inputs + (size_t)b * TT * II;
    if (ks == 0) xh[0][II + j] = h_prev[(size_t)b * HH + j];
    if (tid < II) xh[0][tid] = xin[tid];
    __syncthreads();

    float* outp = out + (size_t)b * TT * HH;
    float* cur = xh[0];
    float* nxt = xh[1];

    for (int t = 0; t < TT; ++t) {
        // prefetch next x into regs (latency hidden under the GEMV)
        float xpre = 0.0f;
        if (tid < II) {
            const int tn = (t + 1 < TT) ? (t + 1) : (TT - 1);
            xpre = xin[(size_t)tn * II + tid];
        }

        // ---- 192 FMAs: 4 gate rows x 48 k, 4 independent chains
        float a0 = bias[0], a1 = bias[1], a2 = bias[2], a3 = bias[3];
        const float4* xc = (const float4*)(cur + k0);
        #pragma unroll
        for (int g = 0; g < KPT / 4; ++g) {
            const float4 v = xc[g];   // 4 distinct addrs/wave -> <=2-way alias = free
            a0 = fmaf(w[0][4*g+0], v.x, a0); a1 = fmaf(w[1][4*g+0], v.x, a1);
            a2 = fmaf(w[2][4*g+0], v.x, a2); a3 = fmaf(w[3][4*g+0], v.x, a3);
            a0 = fmaf(w[0][4*g+1], v.y, a0); a1 = fmaf(w[1][4*g+1], v.y, a1);
            a2 = fmaf(w[2][4*g+1], v.y, a2); a3 = fmaf(w[3][4*g+1], v.y, a3);
            a0 = fmaf(w[0][4*g+2], v.z, a0); a1 = fmaf(w[1][4*g+2], v.z, a1);
            a2 = fmaf(w[2][4*g+2], v.z, a2); a3 = fmaf(w[3][4*g+2], v.z, a3);
            a0 = fmaf(w[0][4*g+3], v.w, a0); a1 = fmaf(w[1][4*g+3], v.w, a1);
            a2 = fmaf(w[2][4*g+3], v.w, a2); a3 = fmaf(w[3][4*g+3], v.w, a3);
        }

        // ---- 2-stage butterfly over the quad (ks = lane&3): pure VALU DPP
        a0 += dpp_xor1(a0); a0 += dpp_xor2(a0);
        a1 += dpp_xor1(a1); a1 += dpp_xor2(a1);
        a2 += dpp_xor1(a2); a2 += dpp_xor2(a2);
        a3 += dpp_xor1(a3); a3 += dpp_xor2(a3);

        // ---- gates + state update, all quad lanes redundantly (no divergence)
        const float ig = fast_sigmoid(a0);
        const float fg = fast_sigmoid(a1);
        const float gg = fast_tanh(a2);
        const float og = fast_sigmoid(a3);
        c = fmaf(fg, c, ig * gg);
        h = og * fast_tanh(c);

        if (ks == 0) {
            nxt[II + j] = h;
            outp[(size_t)t * HH + j] = h;
        }
        if (tid < II) nxt[tid] = xpre;
        __syncthreads();                 // single barrier per step
        float* tmp = cur; cur = nxt; nxt = tmp;
    }

    if (ks == 0) {
        out[(size_t)BB * TT * HH + (size_t)b * HH + j] = h;
        out[(size_t)BB * TT * HH + (size_t)BB * HH + (size_t)b * HH + j] = c;
    }
}

extern "C" void kernel_launch(void* const* d_in, const int* in_sizes, int n_in,
                              void* d_out, int out_size, void* d_ws, size_t ws_size,
                              hipStream_t stream) {
    const float* inputs = (const float*)d_in[0];
    const float* h_prev = (const float*)d_in[1];
    const float* c_prev = (const float*)d_in[2];
    const float* W_ih   = (const float*)d_in[3];
    const float* W_hh   = (const float*)d_in[4];
    const float* b_ih   = (const float*)d_in[5];
    const float* b_hh   = (const float*)d_in[6];
    float* outp = (float*)d_out;

    lstm_r6<<<dim3(BB), dim3(NTH), 0, stream>>>(
        inputs, h_prev, c_prev, W_ih, W_hh, b_ih, b_hh, outp);
}